// Round 3
// baseline (6175.746 us; speedup 1.0000x reference)
//
#include <hip/hip_runtime.h>
#include <stdint.h>

// Problem constants (from reference)
#define MA    50           // MAX_ATOMS
#define NGF   30           // N_GRAPH_FEAT
#define NAF   75           // N_ATOM_FEAT
#define NA    6400         // N_ATOMS = 50*128
#define H     100          // HIDDEN
#define GFS   51           // gf slots per row (MAX_ATOMS+1)
#define SLOTP 32           // padded slot stride in floats (16B-aligned slot bases)
#define RPB   8            // rows per block
#define NTHR  512          // 8 waves

// Detect whether calculation_masks arrived as 1-byte bools or int32.
__global__ void detect_mask(const uint8_t* __restrict__ cm, int* __restrict__ flag) {
    if (threadIdx.x == 0 && blockIdx.x == 0) {
        int f = 0;
        for (int pos = 1; pos < 4096; ++pos) {
            if ((pos & 3) != 0 && cm[pos] != 0) { f = 1; break; }
        }
        *flag = f;   // 1 => bool (1 byte/elem), 0 => int32
    }
}

__global__ __launch_bounds__(NTHR, 4) void dag_fused(
    const float* __restrict__ af,      // (NA, NAF)
    const int*   __restrict__ parents, // (NA, MA, MA)
    const int*   __restrict__ orders,  // (NA, MA)
    const void*  __restrict__ cmask,   // (NA, MA) bool-or-int32
    const float* __restrict__ W0,      // (NIN, H) row-major
    const float* __restrict__ b0,      // (H)
    const float* __restrict__ W1,      // (H, NGF)
    const float* __restrict__ b1,      // (NGF)
    const int*   __restrict__ flagp,
    float*       __restrict__ dout)    // (NA, NGF)
{
    __shared__ float   gfl[RPB][GFS * SLOTP];  // 52,224 B — padded DAG state
    __shared__ float   afx[RPB][76];           //  2,432 B — atom-feature part (75 + pad)
    __shared__ float   hs[RPB][H];             //  3,200 B
    __shared__ float   P1[4][RPB][H];          // 12,800 B — reduction buffer 1
    __shared__ float   P2[2][RPB][H];          //  6,400 B — reduction buffer 2
    __shared__ uint8_t slots[RPB][56];         //    448 B (49 used)
    __shared__ int     colc[RPB];
    __shared__ int     maskc[RPB];
    // total ~75.8 KB -> 2 blocks/CU

    const int tid  = threadIdx.x;
    const int w    = tid >> 6;      // wave 0..7
    const int jp   = tid & 63;      // lane: column-pair index (active < 50)
    const int row0 = blockIdx.x * RPB;
    const int flag = *flagp;

    // zero gf state (padded; == reference gf0)
    for (int e = tid; e < RPB * GFS * SLOTP / 4; e += NTHR)
        ((float4*)gfl)[e] = float4{0.f, 0.f, 0.f, 0.f};

    for (int t = 0; t < MA; ++t) {
        // ---- gather: af part, parent slots, col/mask ----
        for (int e = tid; e < RPB * NAF; e += NTHR) {
            int r = e / NAF, k = e - r * NAF;
            int order = orders[(row0 + r) * MA + t];
            afx[r][k] = af[(size_t)order * NAF + k];
        }
        for (int e = tid; e < RPB * (MA - 1); e += NTHR) {
            int r = e / (MA - 1), p = e - r * (MA - 1);
            slots[r][p] = (uint8_t)parents[((size_t)(row0 + r) * MA + t) * MA + 1 + p];
        }
        if (tid < RPB) {
            int i = row0 + tid;
            colc[tid] = parents[((size_t)i * MA + t) * MA];
            int m;
            if (flag) m = ((const uint8_t*)cmask)[i * MA + t] != 0;
            else      m = ((const int*)  cmask)[i * MA + t] != 0;
            maskc[tid] = m;
        }
        __syncthreads();

        // ---- phase 2: h = x @ W0; wave-level K-split, J=2 cols, R=8 rows ----
        float2 acc[RPB];
        #pragma unroll
        for (int r = 0; r < RPB; ++r) acc[r] = float2{0.f, 0.f};

        if (jp < 50) {
            if (w == 0) {
                // atom-feature part: k = 0..74
                const float* wrow = W0 + 2 * jp;
                #pragma unroll
                for (int c0 = 0; c0 < 72; c0 += 24) {
                    float2 wv[24];
                    #pragma unroll
                    for (int c = 0; c < 24; ++c)
                        wv[c] = *(const float2*)(wrow + (size_t)(c0 + c) * H);
                    #pragma unroll
                    for (int r = 0; r < RPB; ++r) {
                        const float* xb = &afx[r][c0];
                        #pragma unroll
                        for (int q = 0; q < 6; ++q) {
                            float4 xq = *(const float4*)(xb + 4 * q);
                            acc[r].x = fmaf(xq.x, wv[4*q+0].x, acc[r].x);
                            acc[r].y = fmaf(xq.x, wv[4*q+0].y, acc[r].y);
                            acc[r].x = fmaf(xq.y, wv[4*q+1].x, acc[r].x);
                            acc[r].y = fmaf(xq.y, wv[4*q+1].y, acc[r].y);
                            acc[r].x = fmaf(xq.z, wv[4*q+2].x, acc[r].x);
                            acc[r].y = fmaf(xq.z, wv[4*q+2].y, acc[r].y);
                            acc[r].x = fmaf(xq.w, wv[4*q+3].x, acc[r].x);
                            acc[r].y = fmaf(xq.w, wv[4*q+3].y, acc[r].y);
                        }
                    }
                }
                // tail k = 72..74
                {
                    float2 wv[3];
                    #pragma unroll
                    for (int c = 0; c < 3; ++c)
                        wv[c] = *(const float2*)(wrow + (size_t)(72 + c) * H);
                    #pragma unroll
                    for (int r = 0; r < RPB; ++r) {
                        float2 xp = *(const float2*)(&afx[r][72]);
                        float  xl = afx[r][74];
                        acc[r].x = fmaf(xp.x, wv[0].x, acc[r].x);
                        acc[r].y = fmaf(xp.x, wv[0].y, acc[r].y);
                        acc[r].x = fmaf(xp.y, wv[1].x, acc[r].x);
                        acc[r].y = fmaf(xp.y, wv[1].y, acc[r].y);
                        acc[r].x = fmaf(xl,   wv[2].x, acc[r].x);
                        acc[r].y = fmaf(xl,   wv[2].y, acc[r].y);
                    }
                }
            } else {
                // parent slots: wave w handles p = (w-1)*7 .. (w-1)*7+6
                const int p0 = (w - 1) * 7;
                for (int pp = 0; pp < 7; ++pp) {
                    const int gp = p0 + pp;
                    const float* wrow = W0 + (size_t)(NAF + gp * NGF) * H + 2 * jp;
                    const float* xb[RPB];
                    #pragma unroll
                    for (int r = 0; r < RPB; ++r)
                        xb[r] = &gfl[r][(int)slots[r][gp] * SLOTP];
                    // chunk A: c = 0..15
                    {
                        float2 wv[16];
                        #pragma unroll
                        for (int c = 0; c < 16; ++c)
                            wv[c] = *(const float2*)(wrow + (size_t)c * H);
                        #pragma unroll
                        for (int r = 0; r < RPB; ++r) {
                            #pragma unroll
                            for (int q = 0; q < 4; ++q) {
                                float4 xq = *(const float4*)(xb[r] + 4 * q);
                                acc[r].x = fmaf(xq.x, wv[4*q+0].x, acc[r].x);
                                acc[r].y = fmaf(xq.x, wv[4*q+0].y, acc[r].y);
                                acc[r].x = fmaf(xq.y, wv[4*q+1].x, acc[r].x);
                                acc[r].y = fmaf(xq.y, wv[4*q+1].y, acc[r].y);
                                acc[r].x = fmaf(xq.z, wv[4*q+2].x, acc[r].x);
                                acc[r].y = fmaf(xq.z, wv[4*q+2].y, acc[r].y);
                                acc[r].x = fmaf(xq.w, wv[4*q+3].x, acc[r].x);
                                acc[r].y = fmaf(xq.w, wv[4*q+3].y, acc[r].y);
                            }
                        }
                    }
                    // chunk B: c = 16..29
                    {
                        float2 wv[14];
                        #pragma unroll
                        for (int c = 0; c < 14; ++c)
                            wv[c] = *(const float2*)(wrow + (size_t)(16 + c) * H);
                        #pragma unroll
                        for (int r = 0; r < RPB; ++r) {
                            const float* xb2 = xb[r] + 16;
                            #pragma unroll
                            for (int q = 0; q < 3; ++q) {
                                float4 xq = *(const float4*)(xb2 + 4 * q);
                                acc[r].x = fmaf(xq.x, wv[4*q+0].x, acc[r].x);
                                acc[r].y = fmaf(xq.x, wv[4*q+0].y, acc[r].y);
                                acc[r].x = fmaf(xq.y, wv[4*q+1].x, acc[r].x);
                                acc[r].y = fmaf(xq.y, wv[4*q+1].y, acc[r].y);
                                acc[r].x = fmaf(xq.z, wv[4*q+2].x, acc[r].x);
                                acc[r].y = fmaf(xq.z, wv[4*q+2].y, acc[r].y);
                                acc[r].x = fmaf(xq.w, wv[4*q+3].x, acc[r].x);
                                acc[r].y = fmaf(xq.w, wv[4*q+3].y, acc[r].y);
                            }
                            float2 xp = *(const float2*)(xb[r] + 28);
                            acc[r].x = fmaf(xp.x, wv[12].x, acc[r].x);
                            acc[r].y = fmaf(xp.x, wv[12].y, acc[r].y);
                            acc[r].x = fmaf(xp.y, wv[13].x, acc[r].x);
                            acc[r].y = fmaf(xp.y, wv[13].y, acc[r].y);
                        }
                    }
                }
            }
        }

        // ---- reduction tree: 8 wave-partials -> hs ----
        if (jp < 50 && w >= 4) {
            #pragma unroll
            for (int r = 0; r < RPB; ++r)
                *(float2*)&P1[w - 4][r][2 * jp] = acc[r];
        }
        __syncthreads();
        if (jp < 50 && w < 4) {
            #pragma unroll
            for (int r = 0; r < RPB; ++r) {
                float2 p = *(const float2*)&P1[w][r][2 * jp];
                acc[r].x += p.x; acc[r].y += p.y;
            }
            if (w >= 2) {
                #pragma unroll
                for (int r = 0; r < RPB; ++r)
                    *(float2*)&P2[w - 2][r][2 * jp] = acc[r];
            }
        }
        __syncthreads();
        if (jp < 50 && w < 2) {
            #pragma unroll
            for (int r = 0; r < RPB; ++r) {
                float2 p = *(const float2*)&P2[w][r][2 * jp];
                acc[r].x += p.x; acc[r].y += p.y;
            }
            if (w == 1) {
                #pragma unroll
                for (int r = 0; r < RPB; ++r)
                    *(float2*)&P1[0][r][2 * jp] = acc[r];
            }
        }
        __syncthreads();
        if (jp < 50 && w == 0) {
            float2 b0v = *(const float2*)(b0 + 2 * jp);
            #pragma unroll
            for (int r = 0; r < RPB; ++r) {
                float2 p = *(const float2*)&P1[0][r][2 * jp];
                float hx = acc[r].x + p.x + b0v.x;
                float hy = acc[r].y + p.y + b0v.y;
                hs[r][2 * jp]     = fmaxf(hx, 0.f);
                hs[r][2 * jp + 1] = fmaxf(hy, 0.f);
            }
        }
        __syncthreads();

        // ---- phase 3: out = relu(h @ W1 + b1); masked scatter into LDS gf ----
        if (tid < RPB * NGF) {
            const int r  = tid / NGF;
            const int c  = tid - r * NGF;
            float a = b1[c];
            #pragma unroll 4
            for (int k = 0; k < H; ++k)
                a = fmaf(hs[r][k], W1[k * NGF + c], a);
            a = fmaxf(a, 0.f);
            if (maskc[r]) gfl[r][colc[r] * SLOTP + c] = a;
            if (t == MA - 1) dout[(row0 + r) * NGF + c] = maskc[r] ? a : 0.f;
        }
        __syncthreads();   // protect gfl/slots/afx before next step
    }
}

extern "C" void kernel_launch(void* const* d_in, const int* in_sizes, int n_in,
                              void* d_out, int out_size, void* d_ws, size_t ws_size,
                              hipStream_t stream) {
    const float* af      = (const float*)d_in[0];
    const int*   parents = (const int*)  d_in[1];
    const int*   orders  = (const int*)  d_in[2];
    const void*  cmask   =               d_in[3];
    // d_in[4] = n_atoms scalar (fixed 6400), unused
    const float* W0      = (const float*)d_in[5];
    const float* b0      = (const float*)d_in[6];
    const float* W1      = (const float*)d_in[7];
    const float* b1      = (const float*)d_in[8];

    int*   flagp = (int*)d_ws;
    float* dout  = (float*)d_out;

    detect_mask<<<1, 64, 0, stream>>>((const uint8_t*)cmask, flagp);
    dag_fused<<<NA / RPB, NTHR, 0, stream>>>(
        af, parents, orders, cmask, W0, b0, W1, b1, flagp, dout);
}

// Round 4
// 3183.063 us; speedup vs baseline: 1.9402x; 1.9402x over previous
//
#include <hip/hip_runtime.h>
#include <stdint.h>

// Problem constants (from reference)
#define MA    50           // MAX_ATOMS
#define NGF   30           // N_GRAPH_FEAT
#define NAF   75           // N_ATOM_FEAT
#define NA    6400         // N_ATOMS = 50*128
#define H     100          // HIDDEN
#define GFS   51           // gf slots per row (MAX_ATOMS+1)
#define SLOTP 32           // padded slot stride in floats (slot bases 128B-aligned)
#define AFP   80           // padded afx stride (16B-aligned rows)
#define RPB   8            // rows per block
#define NTHR  512          // 8 waves

// Detect whether calculation_masks arrived as 1-byte bools or int32.
__global__ void detect_mask(const uint8_t* __restrict__ cm, int* __restrict__ flag) {
    if (threadIdx.x == 0 && blockIdx.x == 0) {
        int f = 0;
        for (int pos = 1; pos < 4096; ++pos) {
            if ((pos & 3) != 0 && cm[pos] != 0) { f = 1; break; }
        }
        *flag = f;   // 1 => bool (1 byte/elem), 0 => int32
    }
}

__global__ __launch_bounds__(NTHR, 4) void dag_fused(
    const float* __restrict__ af,      // (NA, NAF)
    const int*   __restrict__ parents, // (NA, MA, MA)
    const int*   __restrict__ orders,  // (NA, MA)
    const void*  __restrict__ cmask,   // (NA, MA) bool-or-int32
    const float* __restrict__ W0,      // (NIN, H) row-major
    const float* __restrict__ b0,      // (H)
    const float* __restrict__ W1,      // (H, NGF)
    const float* __restrict__ b1,      // (NGF)
    const int*   __restrict__ flagp,
    float*       __restrict__ dout)    // (NA, NGF)
{
    __shared__ float   gfl[RPB][GFS * SLOTP];  // 52,224 B — padded DAG state (pads stay 0)
    __shared__ float   afx[RPB][AFP];          //  2,560 B — atom-feature part (75 + zero pad)
    __shared__ float   hs[RPB][H];             //  3,200 B
    __shared__ float   P1[4][RPB][H];          // 12,800 B
    __shared__ float   P2[2][RPB][H];          //  6,400 B
    __shared__ uint8_t slots[RPB][56];         //    448 B (49 used)
    __shared__ int     colc[RPB];
    __shared__ int     maskc[RPB];
    // total ~78 KB -> 2 blocks/CU (LDS-bound), 16 waves/CU

    const int tid  = threadIdx.x;
    const int w    = tid >> 6;      // wave 0..7
    const int jp   = tid & 63;      // lane: column-pair (active < 50 -> cols 2jp, 2jp+1)
    const int row0 = blockIdx.x * RPB;
    const int flag = *flagp;

    // zero gf state (padded; == reference gf0). Pads never rewritten -> stay 0.
    for (int e = tid; e < RPB * GFS * SLOTP / 4; e += NTHR)
        ((float4*)gfl)[e] = float4{0.f, 0.f, 0.f, 0.f};
    // zero afx pad columns [75..79] once
    if (tid < RPB * (AFP - NAF)) {
        int r = tid / (AFP - NAF), c = tid - r * (AFP - NAF);
        afx[r][NAF + c] = 0.f;
    }

    for (int t = 0; t < MA; ++t) {
        // ---- gather: af part, parent slots, col/mask ----
        for (int e = tid; e < RPB * NAF; e += NTHR) {
            int r = e / NAF, k = e - r * NAF;
            int order = orders[(row0 + r) * MA + t];
            afx[r][k] = af[(size_t)order * NAF + k];
        }
        for (int e = tid; e < RPB * (MA - 1); e += NTHR) {
            int r = e / (MA - 1), p = e - r * (MA - 1);
            slots[r][p] = (uint8_t)parents[((size_t)(row0 + r) * MA + t) * MA + 1 + p];
        }
        if (tid < RPB) {
            int i = row0 + tid;
            colc[tid] = parents[((size_t)i * MA + t) * MA];
            int m;
            if (flag) m = ((const uint8_t*)cmask)[i * MA + t] != 0;
            else      m = ((const int*)  cmask)[i * MA + t] != 0;
            maskc[tid] = m;
        }
        __syncthreads();

        // ---- phase 2: h = x @ W0; wave K-split, J=2 cols, R=8 rows, 4-k chunks ----
        float2 acc[RPB];
        #pragma unroll
        for (int r = 0; r < RPB; ++r) acc[r] = float2{0.f, 0.f};

        if (jp < 50) {
            const float* Wj = W0 + 2 * jp;
            if (w == 0) {
                // atom-feature part: k = 0..74
                #pragma unroll 2
                for (int c0 = 0; c0 < 72; c0 += 4) {
                    float2 w0v = *(const float2*)(Wj + (size_t)(c0 + 0) * H);
                    float2 w1v = *(const float2*)(Wj + (size_t)(c0 + 1) * H);
                    float2 w2v = *(const float2*)(Wj + (size_t)(c0 + 2) * H);
                    float2 w3v = *(const float2*)(Wj + (size_t)(c0 + 3) * H);
                    #pragma unroll
                    for (int r = 0; r < RPB; ++r) {
                        float4 xq = *(const float4*)(&afx[r][c0]);
                        acc[r].x = fmaf(xq.x, w0v.x, acc[r].x);
                        acc[r].y = fmaf(xq.x, w0v.y, acc[r].y);
                        acc[r].x = fmaf(xq.y, w1v.x, acc[r].x);
                        acc[r].y = fmaf(xq.y, w1v.y, acc[r].y);
                        acc[r].x = fmaf(xq.z, w2v.x, acc[r].x);
                        acc[r].y = fmaf(xq.z, w2v.y, acc[r].y);
                        acc[r].x = fmaf(xq.w, w3v.x, acc[r].x);
                        acc[r].y = fmaf(xq.w, w3v.y, acc[r].y);
                    }
                }
                { // tail k = 72..74 (xq.w hits zeroed pad, no FMA emitted for it)
                    float2 w0v = *(const float2*)(Wj + (size_t)72 * H);
                    float2 w1v = *(const float2*)(Wj + (size_t)73 * H);
                    float2 w2v = *(const float2*)(Wj + (size_t)74 * H);
                    #pragma unroll
                    for (int r = 0; r < RPB; ++r) {
                        float4 xq = *(const float4*)(&afx[r][72]);
                        acc[r].x = fmaf(xq.x, w0v.x, acc[r].x);
                        acc[r].y = fmaf(xq.x, w0v.y, acc[r].y);
                        acc[r].x = fmaf(xq.y, w1v.x, acc[r].x);
                        acc[r].y = fmaf(xq.y, w1v.y, acc[r].y);
                        acc[r].x = fmaf(xq.z, w2v.x, acc[r].x);
                        acc[r].y = fmaf(xq.z, w2v.y, acc[r].y);
                    }
                }
            } else {
                // parent slots: wave w handles p = (w-1)*7 .. (w-1)*7+6
                #pragma unroll 1
                for (int pp = 0; pp < 7; ++pp) {
                    const int p = (w - 1) * 7 + pp;
                    const float* wrow = Wj + (size_t)(NAF + p * NGF) * H;
                    int sb[RPB];
                    #pragma unroll
                    for (int r = 0; r < RPB; ++r) sb[r] = (int)slots[r][p] * SLOTP;
                    #pragma unroll 2
                    for (int c0 = 0; c0 < 28; c0 += 4) {
                        float2 w0v = *(const float2*)(wrow + (size_t)(c0 + 0) * H);
                        float2 w1v = *(const float2*)(wrow + (size_t)(c0 + 1) * H);
                        float2 w2v = *(const float2*)(wrow + (size_t)(c0 + 2) * H);
                        float2 w3v = *(const float2*)(wrow + (size_t)(c0 + 3) * H);
                        #pragma unroll
                        for (int r = 0; r < RPB; ++r) {
                            float4 xq = *(const float4*)(&gfl[r][sb[r] + c0]);
                            acc[r].x = fmaf(xq.x, w0v.x, acc[r].x);
                            acc[r].y = fmaf(xq.x, w0v.y, acc[r].y);
                            acc[r].x = fmaf(xq.y, w1v.x, acc[r].x);
                            acc[r].y = fmaf(xq.y, w1v.y, acc[r].y);
                            acc[r].x = fmaf(xq.z, w2v.x, acc[r].x);
                            acc[r].y = fmaf(xq.z, w2v.y, acc[r].y);
                            acc[r].x = fmaf(xq.w, w3v.x, acc[r].x);
                            acc[r].y = fmaf(xq.w, w3v.y, acc[r].y);
                        }
                    }
                    { // tail c = 28..29
                        float2 w0v = *(const float2*)(wrow + (size_t)28 * H);
                        float2 w1v = *(const float2*)(wrow + (size_t)29 * H);
                        #pragma unroll
                        for (int r = 0; r < RPB; ++r) {
                            float2 xp = *(const float2*)(&gfl[r][sb[r] + 28]);
                            acc[r].x = fmaf(xp.x, w0v.x, acc[r].x);
                            acc[r].y = fmaf(xp.x, w0v.y, acc[r].y);
                            acc[r].x = fmaf(xp.y, w1v.x, acc[r].x);
                            acc[r].y = fmaf(xp.y, w1v.y, acc[r].y);
                        }
                    }
                }
            }
        }

        // ---- reduction tree: 8 wave-partials -> hs ----
        if (jp < 50 && w >= 4) {
            #pragma unroll
            for (int r = 0; r < RPB; ++r)
                *(float2*)&P1[w - 4][r][2 * jp] = acc[r];
        }
        __syncthreads();
        if (jp < 50 && w < 4) {
            #pragma unroll
            for (int r = 0; r < RPB; ++r) {
                float2 p = *(const float2*)&P1[w][r][2 * jp];
                acc[r].x += p.x; acc[r].y += p.y;
            }
            if (w >= 2) {
                #pragma unroll
                for (int r = 0; r < RPB; ++r)
                    *(float2*)&P2[w - 2][r][2 * jp] = acc[r];
            }
        }
        __syncthreads();
        if (jp < 50 && w < 2) {
            #pragma unroll
            for (int r = 0; r < RPB; ++r) {
                float2 p = *(const float2*)&P2[w][r][2 * jp];
                acc[r].x += p.x; acc[r].y += p.y;
            }
            if (w == 1) {
                #pragma unroll
                for (int r = 0; r < RPB; ++r)
                    *(float2*)&P1[0][r][2 * jp] = acc[r];
            }
        }
        __syncthreads();
        if (jp < 50 && w == 0) {
            float2 b0v = *(const float2*)(b0 + 2 * jp);
            #pragma unroll
            for (int r = 0; r < RPB; ++r) {
                float2 p = *(const float2*)&P1[0][r][2 * jp];
                hs[r][2 * jp]     = fmaxf(acc[r].x + p.x + b0v.x, 0.f);
                hs[r][2 * jp + 1] = fmaxf(acc[r].y + p.y + b0v.y, 0.f);
            }
        }
        __syncthreads();

        // ---- phase 3: out = relu(h @ W1 + b1); masked scatter into LDS gf ----
        if (tid < RPB * NGF) {
            const int r = tid / NGF;
            const int c = tid - r * NGF;
            float a = b1[c];
            #pragma unroll 4
            for (int k = 0; k < H; ++k)
                a = fmaf(hs[r][k], W1[k * NGF + c], a);
            a = fmaxf(a, 0.f);
            if (maskc[r]) gfl[r][colc[r] * SLOTP + c] = a;
            if (t == MA - 1) dout[(row0 + r) * NGF + c] = maskc[r] ? a : 0.f;
        }
        __syncthreads();   // protect gfl/slots/afx before next step
    }
}

extern "C" void kernel_launch(void* const* d_in, const int* in_sizes, int n_in,
                              void* d_out, int out_size, void* d_ws, size_t ws_size,
                              hipStream_t stream) {
    const float* af      = (const float*)d_in[0];
    const int*   parents = (const int*)  d_in[1];
    const int*   orders  = (const int*)  d_in[2];
    const void*  cmask   =               d_in[3];
    // d_in[4] = n_atoms scalar (fixed 6400), unused
    const float* W0      = (const float*)d_in[5];
    const float* b0      = (const float*)d_in[6];
    const float* W1      = (const float*)d_in[7];
    const float* b1      = (const float*)d_in[8];

    int*   flagp = (int*)d_ws;
    float* dout  = (float*)d_out;

    detect_mask<<<1, 64, 0, stream>>>((const uint8_t*)cmask, flagp);
    dag_fused<<<NA / RPB, NTHR, 0, stream>>>(
        af, parents, orders, cmask, W0, b0, W1, b1, flagp, dout);
}

// Round 5
// 2550.046 us; speedup vs baseline: 2.4218x; 1.2482x over previous
//
#include <hip/hip_runtime.h>
#include <stdint.h>

// Problem constants
#define MA    50
#define NGF   30
#define NAF   75
#define NA    6400
#define H     100
#define GFS   51
#define RPB   16          // rows per block = MFMA M
#define NTHR  512         // 8 waves
#define GROW  1640        // gfh row stride (fp16 elems): 51*32 + 8 pad
#define AFW   104         // afh row stride (96 + 8)
#define HW    136         // hh row stride (128 + 8)
#define NT0   7           // W0 N-tiles (100 -> 112)
#define KT0   52          // W0 K-tiles (3 af + 49 slots)
#define NT1   2           // W1 N-tiles (30 -> 32)
#define KT1   4           // W1 K-tiles (100 -> 128)

typedef _Float16 f16;
typedef _Float16 f16x8 __attribute__((ext_vector_type(8)));
typedef float    f32x4 __attribute__((ext_vector_type(4)));

// ---- mask dtype detection (bool vs int32) ----
__global__ void detect_mask(const uint8_t* __restrict__ cm, int* __restrict__ flag) {
    if (threadIdx.x == 0 && blockIdx.x == 0) {
        int f = 0;
        for (int pos = 1; pos < 4096; ++pos)
            if ((pos & 3) != 0 && cm[pos] != 0) { f = 1; break; }
        *flag = f;
    }
}

// ---- pack W0 into B-fragment order: [nt][kt][lane][8], hi + scaled lo ----
__global__ void pack_w0(const float* __restrict__ W0, f16* __restrict__ ph, f16* __restrict__ pl) {
    int idx = blockIdx.x * 256 + threadIdx.x;       // (nt*KT0 + kt)*64 + lane
    if (idx >= NT0 * KT0 * 64) return;
    int lane = idx & 63;
    int ktn  = idx >> 6;
    int nt = ktn / KT0, kt = ktn % KT0;
    int col = nt * 16 + (lane & 15);
    #pragma unroll
    for (int e = 0; e < 8; ++e) {
        int k = kt * 32 + (lane >> 4) * 8 + e;      // padded K index within schema
        int kr = -1;
        if (kt < 3) { if (k < NAF) kr = k; }
        else {
            int kk = k - kt * 32;                    // 0..31
            if (kk < NGF) kr = NAF + (kt - 3) * NGF + kk;
        }
        float wv = (kr >= 0 && col < H) ? W0[(size_t)kr * H + col] : 0.f;
        f16 hi = (f16)wv;
        f16 lo = (f16)((wv - (float)hi) * 1024.f);
        ph[(size_t)idx * 8 + e] = hi;
        pl[(size_t)idx * 8 + e] = lo;
    }
}

// ---- pack W1: [nt2][kt2][lane][8] ----
__global__ void pack_w1(const float* __restrict__ W1, f16* __restrict__ ph, f16* __restrict__ pl) {
    int idx = blockIdx.x * 256 + threadIdx.x;
    if (idx >= NT1 * KT1 * 64) return;
    int lane = idx & 63;
    int ktn  = idx >> 6;
    int nt = ktn / KT1, kt = ktn % KT1;
    int col = nt * 16 + (lane & 15);
    #pragma unroll
    for (int e = 0; e < 8; ++e) {
        int k = kt * 32 + (lane >> 4) * 8 + e;
        float wv = (k < H && col < NGF) ? W1[(size_t)k * NGF + col] : 0.f;
        f16 hi = (f16)wv;
        f16 lo = (f16)((wv - (float)hi) * 1024.f);
        ph[(size_t)idx * 8 + e] = hi;
        pl[(size_t)idx * 8 + e] = lo;
    }
}

__global__ __launch_bounds__(NTHR, 4) void dag_mfma(
    const float* __restrict__ af,      // (NA, NAF) f32
    const int*   __restrict__ parents, // (NA, MA, MA)
    const int*   __restrict__ orders,  // (NA, MA)
    const void*  __restrict__ cmask,   // (NA, MA)
    const float* __restrict__ b0,      // (H)
    const float* __restrict__ b1,      // (NGF)
    const f16*   __restrict__ w0h, const f16* __restrict__ w0l,
    const f16*   __restrict__ w1h, const f16* __restrict__ w1l,
    const int*   __restrict__ flagp,
    float*       __restrict__ dout)    // (NA, NGF)
{
    __shared__ f16     gfh[RPB][GROW];   // 52,480 B  DAG state, fp16, slot stride 32
    __shared__ f16     afh[RPB][AFW];    //  3,328 B  atom features (k-pad zeroed)
    __shared__ f16     hh[RPB][HW];      //  4,352 B  hidden (k-pad zeroed)
    __shared__ float   outl[RPB][32];    //  2,048 B
    __shared__ uint8_t slots[RPB][52];   //    832 B
    __shared__ int     colc[RPB];
    __shared__ int     maskc[RPB];
    // total ~63.2 KB -> 2 blocks/CU

    const int tid  = threadIdx.x;
    const int w    = tid >> 6;
    const int lane = tid & 63;
    const int row0 = blockIdx.x * RPB;
    const int flag = *flagp;
    const int mrow = lane & 15;   // A-row / C-col index
    const int kg   = lane >> 4;   // k-octet group

    // zero LDS state once (pads stay zero forever)
    {
        f16x8 z = 0;
        for (int e = tid; e < RPB * GROW / 8; e += NTHR) ((f16x8*)gfh)[e] = z;
        for (int e = tid; e < RPB * AFW  / 8; e += NTHR) ((f16x8*)afh)[e] = z;
        for (int e = tid; e < RPB * HW   / 8; e += NTHR) ((f16x8*)hh)[e]  = z;
    }
    __syncthreads();

    for (int t = 0; t < MA; ++t) {
        // ---- gather ----
        for (int e = tid; e < RPB * NAF; e += NTHR) {
            int r = e / NAF, k = e - r * NAF;
            int order = orders[(row0 + r) * MA + t];
            afh[r][k] = (f16)af[(size_t)order * NAF + k];
        }
        for (int e = tid; e < RPB * (MA - 1); e += NTHR) {
            int r = e / (MA - 1), p = e - r * (MA - 1);
            slots[r][p] = (uint8_t)parents[((size_t)(row0 + r) * MA + t) * MA + 1 + p];
        }
        if (tid < RPB) {
            int i = row0 + tid;
            colc[tid] = parents[((size_t)i * MA + t) * MA];
            maskc[tid] = flag ? (((const uint8_t*)cmask)[i * MA + t] != 0)
                              : (((const int*)  cmask)[i * MA + t] != 0);
        }
        __syncthreads();

        // ---- W0 stage: wave nt computes h cols 16nt..16nt+15 for all 16 rows ----
        if (w < NT0) {
            const int nt = w;
            f32x4 ah = {0.f, 0.f, 0.f, 0.f};
            f32x4 al = {0.f, 0.f, 0.f, 0.f};
            const f16x8* bh = (const f16x8*)w0h + (size_t)nt * KT0 * 64 + lane;
            const f16x8* bl = (const f16x8*)w0l + (size_t)nt * KT0 * 64 + lane;
            #pragma unroll
            for (int kt = 0; kt < 3; ++kt) {
                f16x8 a = *(const f16x8*)&afh[mrow][kt * 32 + kg * 8];
                ah = __builtin_amdgcn_mfma_f32_16x16x32_f16(a, bh[(size_t)kt * 64], ah, 0, 0, 0);
                al = __builtin_amdgcn_mfma_f32_16x16x32_f16(a, bl[(size_t)kt * 64], al, 0, 0, 0);
            }
            #pragma unroll 4
            for (int p = 0; p < MA - 1; ++p) {
                int slot = slots[mrow][p];
                f16x8 a = *(const f16x8*)&gfh[mrow][slot * 32 + kg * 8];
                ah = __builtin_amdgcn_mfma_f32_16x16x32_f16(a, bh[(size_t)(3 + p) * 64], ah, 0, 0, 0);
                al = __builtin_amdgcn_mfma_f32_16x16x32_f16(a, bl[(size_t)(3 + p) * 64], al, 0, 0, 0);
            }
            const int hcol = nt * 16 + mrow;
            if (hcol < H) {
                float bb = b0[hcol];
                #pragma unroll
                for (int i = 0; i < 4; ++i) {
                    int hrow = kg * 4 + i;
                    float hv = ah[i] + al[i] * (1.f / 1024.f) + bb;
                    hh[hrow][hcol] = (f16)fmaxf(hv, 0.f);
                }
            }
        }
        __syncthreads();

        // ---- W1 stage: waves 0,1 compute out cols 16nt..16nt+15 ----
        if (w < NT1) {
            const int nt = w;
            f32x4 ah = {0.f, 0.f, 0.f, 0.f};
            f32x4 al = {0.f, 0.f, 0.f, 0.f};
            const f16x8* bh = (const f16x8*)w1h + (size_t)nt * KT1 * 64 + lane;
            const f16x8* bl = (const f16x8*)w1l + (size_t)nt * KT1 * 64 + lane;
            #pragma unroll
            for (int kt = 0; kt < KT1; ++kt) {
                f16x8 a = *(const f16x8*)&hh[mrow][kt * 32 + kg * 8];
                ah = __builtin_amdgcn_mfma_f32_16x16x32_f16(a, bh[(size_t)kt * 64], ah, 0, 0, 0);
                al = __builtin_amdgcn_mfma_f32_16x16x32_f16(a, bl[(size_t)kt * 64], al, 0, 0, 0);
            }
            const int ocol = nt * 16 + mrow;
            if (ocol < NGF) {
                float bb = b1[ocol];
                #pragma unroll
                for (int i = 0; i < 4; ++i) {
                    int orow = kg * 4 + i;
                    float ov = ah[i] + al[i] * (1.f / 1024.f) + bb;
                    outl[orow][ocol] = fmaxf(ov, 0.f);
                }
            }
        }
        __syncthreads();

        // ---- scatter into LDS gf; final output at t = MA-1 ----
        if (tid < RPB * NGF) {
            int r = tid / NGF, c = tid - r * NGF;
            float v = outl[r][c];
            if (maskc[r]) gfh[r][colc[r] * 32 + c] = (f16)v;
            if (t == MA - 1) dout[(row0 + r) * NGF + c] = maskc[r] ? v : 0.f;
        }
        __syncthreads();
    }
}

extern "C" void kernel_launch(void* const* d_in, const int* in_sizes, int n_in,
                              void* d_out, int out_size, void* d_ws, size_t ws_size,
                              hipStream_t stream) {
    const float* af      = (const float*)d_in[0];
    const int*   parents = (const int*)  d_in[1];
    const int*   orders  = (const int*)  d_in[2];
    const void*  cmask   =               d_in[3];
    // d_in[4] = n_atoms scalar, unused
    const float* W0      = (const float*)d_in[5];
    const float* b0      = (const float*)d_in[6];
    const float* W1      = (const float*)d_in[7];
    const float* b1      = (const float*)d_in[8];

    // workspace layout
    char* ws = (char*)d_ws;
    f16* w0h = (f16*)(ws);                                  // 372,736 B
    f16* w0l = (f16*)(ws + 372736);                         // 372,736 B
    f16* w1h = (f16*)(ws + 745472);                         //   8,192 B
    f16* w1l = (f16*)(ws + 753664);                         //   8,192 B
    int* flagp = (int*)(ws + 761856);
    float* dout = (float*)d_out;

    detect_mask<<<1, 64, 0, stream>>>((const uint8_t*)cmask, flagp);
    pack_w0<<<(NT0 * KT0 * 64 + 255) / 256, 256, 0, stream>>>(W0, w0h, w0l);
    pack_w1<<<(NT1 * KT1 * 64 + 255) / 256, 256, 0, stream>>>(W1, w1h, w1l);

    dag_mfma<<<NA / RPB, NTHR, 0, stream>>>(
        af, parents, orders, cmask, b0, b1, w0h, w0l, w1h, w1l, flagp, dout);
}

// Round 6
// 875.030 us; speedup vs baseline: 7.0578x; 2.9142x over previous
//
#include <hip/hip_runtime.h>
#include <stdint.h>

// Problem constants
#define MA    50
#define NGF   30
#define NAF   75
#define NA    6400
#define H     100
#define GFS   51
#define RPB   32          // rows per block (2 MFMA M-tiles)
#define NTHR  512         // 8 waves
#define GROW  1640        // gfh row stride (f16): 51*32 + 8
#define AFW   104         // afh row stride (96 + 8)
#define HW    136         // hh row stride (128 + 8)
#define NT0   7           // W0 N-tiles (100 -> 112)
#define KT0   52          // W0 K-tiles (3 af + 49 slots)
#define NT1   2           // W1 N-tiles
#define KT1   4           // W1 K-tiles
#define KSTREAM 8         // W0 K-tiles streamed from L2 per step
#define KREG  44          // W0 K-tiles resident in VGPRs (KT0 - KSTREAM)

typedef _Float16 f16;
typedef _Float16 f16x8 __attribute__((ext_vector_type(8)));
typedef float    f32x4 __attribute__((ext_vector_type(4)));

#define MFMA16(a, b, c) __builtin_amdgcn_mfma_f32_16x16x32_f16((a), (b), (c), 0, 0, 0)

// ---- mask dtype detection (bool vs int32) ----
__global__ void detect_mask(const uint8_t* __restrict__ cm, int* __restrict__ flag) {
    if (threadIdx.x == 0 && blockIdx.x == 0) {
        int f = 0;
        for (int pos = 1; pos < 4096; ++pos)
            if ((pos & 3) != 0 && cm[pos] != 0) { f = 1; break; }
        *flag = f;
    }
}

// ---- pack W0 into B-fragment order [nt][kt][lane][8], single fp16 ----
__global__ void pack_w0(const float* __restrict__ W0, f16* __restrict__ ph) {
    int idx = blockIdx.x * 256 + threadIdx.x;
    if (idx >= NT0 * KT0 * 64) return;
    int lane = idx & 63;
    int ktn  = idx >> 6;
    int nt = ktn / KT0, kt = ktn % KT0;
    int col = nt * 16 + (lane & 15);
    #pragma unroll
    for (int e = 0; e < 8; ++e) {
        int k = kt * 32 + (lane >> 4) * 8 + e;
        int kr = -1;
        if (kt < 3) { if (k < NAF) kr = k; }
        else {
            int kk = k - kt * 32;
            if (kk < NGF) kr = NAF + (kt - 3) * NGF + kk;
        }
        float wv = (kr >= 0 && col < H) ? W0[(size_t)kr * H + col] : 0.f;
        ph[(size_t)idx * 8 + e] = (f16)wv;
    }
}

// ---- pack W1 [nt][kt][lane][8], hi + scaled lo ----
__global__ void pack_w1(const float* __restrict__ W1, f16* __restrict__ ph, f16* __restrict__ pl) {
    int idx = blockIdx.x * 256 + threadIdx.x;
    if (idx >= NT1 * KT1 * 64) return;
    int lane = idx & 63;
    int ktn  = idx >> 6;
    int nt = ktn / KT1, kt = ktn % KT1;
    int col = nt * 16 + (lane & 15);
    #pragma unroll
    for (int e = 0; e < 8; ++e) {
        int k = kt * 32 + (lane >> 4) * 8 + e;
        float wv = (k < H && col < NGF) ? W1[(size_t)k * NGF + col] : 0.f;
        f16 hi = (f16)wv;
        ph[(size_t)idx * 8 + e] = hi;
        pl[(size_t)idx * 8 + e] = (f16)((wv - (float)hi) * 1024.f);
    }
}

__global__ __launch_bounds__(NTHR, 2) void dag_mfma(
    const float* __restrict__ af,      // (NA, NAF) f32
    const int*   __restrict__ parents, // (NA, MA, MA)
    const int*   __restrict__ orders,  // (NA, MA)
    const void*  __restrict__ cmask,   // (NA, MA)
    const float* __restrict__ b0,
    const float* __restrict__ b1,
    const f16*   __restrict__ w0h,
    const f16*   __restrict__ w1h, const f16* __restrict__ w1l,
    const int*   __restrict__ flagp,
    float*       __restrict__ dout)    // (NA, NGF)
{
    __shared__ f16     gfh[RPB][GROW];   // 104,960 B  DAG state (fp16, slot stride 32)
    __shared__ f16     afh[RPB][AFW];    //   6,656 B
    __shared__ f16     hh[RPB][HW];      //   8,704 B
    __shared__ float   outl[RPB][32];    //   4,096 B
    __shared__ uint8_t slots[RPB][52];   //   1,664 B
    __shared__ int     colc[RPB];        //     128 B
    __shared__ int     maskc[RPB];       //     128 B
    __shared__ int     ordl[2][RPB];     //     256 B
    // total 126,592 B -> 1 block/CU, 8 waves (2/SIMD)

    const int tid  = threadIdx.x;
    const int w    = tid >> 6;
    const int lane = tid & 63;
    const int mrow = lane & 15;
    const int kg   = lane >> 4;
    const int row0 = blockIdx.x * RPB;
    const int flag = *flagp;

    // ---- zero LDS state (pads stay zero forever) ----
    {
        f16x8 z = 0;
        for (int e = tid; e < RPB * GROW / 8; e += NTHR) ((f16x8*)gfh)[e] = z;
        for (int e = tid; e < RPB * AFW  / 8; e += NTHR) ((f16x8*)afh)[e] = z;
        for (int e = tid; e < RPB * HW   / 8; e += NTHR) ((f16x8*)hh)[e]  = z;
    }

    // ---- W0 B-fragments resident in VGPRs (kt = KSTREAM..51), loaded once ----
    f16x8 wreg[KREG];
    if (w < NT0) {
        const f16x8* bp = (const f16x8*)w0h + ((size_t)w * KT0 + KSTREAM) * 64 + lane;
        #pragma unroll
        for (int q = 0; q < KREG; ++q) wreg[q] = bp[(size_t)q * 64];
    }

    // per-lane constants
    const int hcol = w * 16 + mrow;                 // waves 0..6: h column
    float b0v = (w < NT0 && hcol < H) ? b0[hcol] : 0.f;
    float b1v0 = 0.f, b1v1 = 0.f;
    if (w == 7) {
        b1v0 = b1[mrow];                            // mrow < 16 < 30
        if (16 + mrow < NGF) b1v1 = b1[16 + mrow];
    }

    // ---- prologue: orders(t=0) into ordl[0] ----
    if (tid >= 384 && tid < 416) {
        int r = tid - 384;
        ordl[0][r] = orders[(size_t)(row0 + r) * MA];
    }
    __syncthreads();

    float afr0 = 0.f, afr1 = 0.f, afr2 = 0.f, afr3 = 0.f, afr4 = 0.f;
    int   slr0 = 0, slr1 = 0, slr2 = 0, slr3 = 0;
    int   colr = 0, mskr = 0, oreg = 0;

    // issue gather loads for step T into regs (af via ordl[T&1])
    auto LOADS = [&](int T) {
        const int* ordb = ordl[T & 1];
        {
            int idx, r, k;
            idx = tid;        r = idx / NAF; k = idx - r * NAF; afr0 = af[(size_t)ordb[r] * NAF + k];
            idx = tid + 512;  r = idx / NAF; k = idx - r * NAF; afr1 = af[(size_t)ordb[r] * NAF + k];
            idx = tid + 1024; r = idx / NAF; k = idx - r * NAF; afr2 = af[(size_t)ordb[r] * NAF + k];
            idx = tid + 1536; r = idx / NAF; k = idx - r * NAF; afr3 = af[(size_t)ordb[r] * NAF + k];
            if (tid < 352) {
                idx = tid + 2048; r = idx / NAF; k = idx - r * NAF;
                afr4 = af[(size_t)ordb[r] * NAF + k];
            }
        }
        {
            int idx, r, p;
            idx = tid;        r = idx / 49; p = idx - r * 49;
            slr0 = __builtin_nontemporal_load(&parents[((size_t)(row0 + r) * MA + T) * MA + 1 + p]);
            idx = tid + 512;  r = idx / 49; p = idx - r * 49;
            slr1 = __builtin_nontemporal_load(&parents[((size_t)(row0 + r) * MA + T) * MA + 1 + p]);
            idx = tid + 1024; r = idx / 49; p = idx - r * 49;
            slr2 = __builtin_nontemporal_load(&parents[((size_t)(row0 + r) * MA + T) * MA + 1 + p]);
            if (tid < 32) {
                idx = tid + 1536; r = idx / 49; p = idx - r * 49;
                slr3 = __builtin_nontemporal_load(&parents[((size_t)(row0 + r) * MA + T) * MA + 1 + p]);
            }
        }
        if (tid >= 416 && tid < 448) {
            int r = tid - 416;
            colr = __builtin_nontemporal_load(&parents[((size_t)(row0 + r) * MA + T) * MA]);
        }
        if (tid >= 448 && tid < 480) {
            int r = tid - 448;
            if (flag) mskr = (int)__builtin_nontemporal_load(&((const uint8_t*)cmask)[(size_t)(row0 + r) * MA + T]);
            else      mskr = __builtin_nontemporal_load(&((const int*)cmask)[(size_t)(row0 + r) * MA + T]);
        }
        if (T + 1 < MA && tid >= 384 && tid < 416) {
            int r = tid - 384;
            oreg = __builtin_nontemporal_load(&orders[(size_t)(row0 + r) * MA + T + 1]);
        }
    };

    LOADS(0);

    for (int t = 0; t < MA; ++t) {
        // ---- phase A: write staged gather(t) to LDS; stage ordl for t+1 ----
        {
            int idx, r, k;
            idx = tid;        r = idx / NAF; k = idx - r * NAF; afh[r][k] = (f16)afr0;
            idx = tid + 512;  r = idx / NAF; k = idx - r * NAF; afh[r][k] = (f16)afr1;
            idx = tid + 1024; r = idx / NAF; k = idx - r * NAF; afh[r][k] = (f16)afr2;
            idx = tid + 1536; r = idx / NAF; k = idx - r * NAF; afh[r][k] = (f16)afr3;
            if (tid < 352) { idx = tid + 2048; r = idx / NAF; k = idx - r * NAF; afh[r][k] = (f16)afr4; }
        }
        {
            int idx, r, p;
            idx = tid;        r = idx / 49; p = idx - r * 49; slots[r][p] = (uint8_t)slr0;
            idx = tid + 512;  r = idx / 49; p = idx - r * 49; slots[r][p] = (uint8_t)slr1;
            idx = tid + 1024; r = idx / 49; p = idx - r * 49; slots[r][p] = (uint8_t)slr2;
            if (tid < 32) { idx = tid + 1536; r = idx / 49; p = idx - r * 49; slots[r][p] = (uint8_t)slr3; }
        }
        if (tid >= 416 && tid < 448) colc[tid - 416]  = colr;
        if (tid >= 448 && tid < 480) maskc[tid - 448] = mskr;
        if (t + 1 < MA && tid >= 384 && tid < 416) ordl[(t + 1) & 1][tid - 384] = oreg;
        __syncthreads();

        // ---- phase B: issue gather loads for t+1 (hidden under MFMA below) ----
        if (t + 1 < MA) LOADS(t + 1);

        // ---- phase C: W0 (waves 0..6): h = relu(x @ W0 + b0) into hh ----
        if (w < NT0) {
            f32x4 acc0 = {0.f, 0.f, 0.f, 0.f};
            f32x4 acc1 = {0.f, 0.f, 0.f, 0.f};
            const f16x8* bsp = (const f16x8*)w0h + (size_t)w * KT0 * 64 + lane;
            f16x8 bs[KSTREAM];
            #pragma unroll
            for (int q = 0; q < KSTREAM; ++q) bs[q] = bsp[(size_t)q * 64];
            // kt 0..2: atom-feature part
            #pragma unroll
            for (int kt = 0; kt < 3; ++kt) {
                f16x8 a0 = *(const f16x8*)&afh[mrow][kt * 32 + kg * 8];
                f16x8 a1 = *(const f16x8*)&afh[16 + mrow][kt * 32 + kg * 8];
                acc0 = MFMA16(a0, bs[kt], acc0);
                acc1 = MFMA16(a1, bs[kt], acc1);
            }
            // kt 3..KSTREAM-1: first parent slots (streamed B)
            #pragma unroll
            for (int kt = 3; kt < KSTREAM; ++kt) {
                int p = kt - 3;
                f16x8 a0 = *(const f16x8*)&gfh[mrow][(int)slots[mrow][p] * 32 + kg * 8];
                f16x8 a1 = *(const f16x8*)&gfh[16 + mrow][(int)slots[16 + mrow][p] * 32 + kg * 8];
                acc0 = MFMA16(a0, bs[kt], acc0);
                acc1 = MFMA16(a1, bs[kt], acc1);
            }
            // kt KSTREAM..51: register-resident B
            #pragma unroll
            for (int q = 0; q < KREG; ++q) {
                int p = KSTREAM - 3 + q;
                f16x8 a0 = *(const f16x8*)&gfh[mrow][(int)slots[mrow][p] * 32 + kg * 8];
                f16x8 a1 = *(const f16x8*)&gfh[16 + mrow][(int)slots[16 + mrow][p] * 32 + kg * 8];
                acc0 = MFMA16(a0, wreg[q], acc0);
                acc1 = MFMA16(a1, wreg[q], acc1);
            }
            if (hcol < H) {
                #pragma unroll
                for (int i = 0; i < 4; ++i) {
                    hh[kg * 4 + i][hcol]      = (f16)fmaxf(acc0[i] + b0v, 0.f);
                    hh[16 + kg * 4 + i][hcol] = (f16)fmaxf(acc1[i] + b0v, 0.f);
                }
            }
        }
        __syncthreads();

        // ---- phase D: W1 (wave 7): out = relu(h @ W1 + b1) into outl ----
        if (w == 7) {
            #pragma unroll
            for (int nt2 = 0; nt2 < NT1; ++nt2) {
                f32x4 ah0 = {0.f,0.f,0.f,0.f}, al0 = {0.f,0.f,0.f,0.f};
                f32x4 ah1 = {0.f,0.f,0.f,0.f}, al1 = {0.f,0.f,0.f,0.f};
                const f16x8* bh = (const f16x8*)w1h + (size_t)nt2 * KT1 * 64 + lane;
                const f16x8* bl = (const f16x8*)w1l + (size_t)nt2 * KT1 * 64 + lane;
                #pragma unroll
                for (int kt = 0; kt < KT1; ++kt) {
                    f16x8 a0  = *(const f16x8*)&hh[mrow][kt * 32 + kg * 8];
                    f16x8 a1  = *(const f16x8*)&hh[16 + mrow][kt * 32 + kg * 8];
                    f16x8 bhf = bh[(size_t)kt * 64];
                    f16x8 blf = bl[(size_t)kt * 64];
                    ah0 = MFMA16(a0, bhf, ah0);
                    al0 = MFMA16(a0, blf, al0);
                    ah1 = MFMA16(a1, bhf, ah1);
                    al1 = MFMA16(a1, blf, al1);
                }
                const int ocol = nt2 * 16 + mrow;
                if (ocol < NGF) {
                    float bb = nt2 ? b1v1 : b1v0;
                    #pragma unroll
                    for (int i = 0; i < 4; ++i) {
                        outl[kg * 4 + i][ocol]      = fmaxf(ah0[i] + al0[i] * (1.f/1024.f) + bb, 0.f);
                        outl[16 + kg * 4 + i][ocol] = fmaxf(ah1[i] + al1[i] * (1.f/1024.f) + bb, 0.f);
                    }
                }
            }
        }
        __syncthreads();

        // ---- phase E: masked scatter into gfh; final output at t = MA-1 ----
        #pragma unroll
        for (int q = 0; q < 2; ++q) {
            int e = tid + q * NTHR;
            if (e < RPB * NGF) {
                int r = e / NGF, c = e - r * NGF;
                float v = outl[r][c];
                if (maskc[r]) gfh[r][colc[r] * 32 + c] = (f16)v;
                if (t == MA - 1) dout[(size_t)(row0 + r) * NGF + c] = maskc[r] ? v : 0.f;
            }
        }
        __syncthreads();
    }
}

extern "C" void kernel_launch(void* const* d_in, const int* in_sizes, int n_in,
                              void* d_out, int out_size, void* d_ws, size_t ws_size,
                              hipStream_t stream) {
    const float* af      = (const float*)d_in[0];
    const int*   parents = (const int*)  d_in[1];
    const int*   orders  = (const int*)  d_in[2];
    const void*  cmask   =               d_in[3];
    // d_in[4] = n_atoms scalar, unused
    const float* W0      = (const float*)d_in[5];
    const float* b0      = (const float*)d_in[6];
    const float* W1      = (const float*)d_in[7];
    const float* b1      = (const float*)d_in[8];

    char* ws = (char*)d_ws;
    f16* w0h = (f16*)(ws);               // 372,736 B
    f16* w1h = (f16*)(ws + 372736);      //   8,192 B
    f16* w1l = (f16*)(ws + 380928);      //   8,192 B
    int* flagp = (int*)(ws + 389120);
    float* dout = (float*)d_out;

    detect_mask<<<1, 64, 0, stream>>>((const uint8_t*)cmask, flagp);
    pack_w0<<<(NT0 * KT0 * 64 + 255) / 256, 256, 0, stream>>>(W0, w0h);
    pack_w1<<<(NT1 * KT1 * 64 + 255) / 256, 256, 0, stream>>>(W1, w1h, w1l);

    dag_mfma<<<NA / RPB, NTHR, 0, stream>>>(
        af, parents, orders, cmask, b0, b1, w0h, w1h, w1l, flagp, dout);
}

// Round 8
// 289.184 us; speedup vs baseline: 21.3558x; 3.0259x over previous
//
#include <hip/hip_runtime.h>
#include <stdint.h>

// Problem constants
#define MA    50
#define NGF   30
#define NAF   75
#define NA    6400
#define H     100
#define RPB   32          // rows per block (2 MFMA M-tiles of 16)
#define NTHR  512         // 8 waves
#define NT0P  8           // W0 N-tiles padded (7 real + 1 zero)
#define KT0   52          // W0 K-tiles (3 af + 49 slots)
#define NT1   2           // W1 N-tiles
#define KT1   4           // W1 K-tiles
#define AFW   104         // afh row stride (96 + 8) f16
#define HHW   136         // hh row stride (128 + 8) f16

typedef _Float16 f16;
typedef _Float16 f16x8 __attribute__((ext_vector_type(8)));
typedef float    f32x4 __attribute__((ext_vector_type(4)));

#define MFMA16(a, b, c) __builtin_amdgcn_mfma_f32_16x16x32_f16((a), (b), (c), 0, 0, 0)

// ---- mask dtype detection (bool vs int32), parallel: one wave + ballot ----
__global__ void detect_mask(const uint8_t* __restrict__ cm, int* __restrict__ flag) {
    int tid = threadIdx.x;   // 64
    int any = 0;
    #pragma unroll
    for (int i = 0; i < 64; ++i) {
        int pos = i * 64 + tid;
        if ((pos & 3) != 0 && cm[pos] != 0) any = 1;
    }
    unsigned long long b = __ballot(any != 0);
    if (tid == 0) *flag = (b != 0ULL) ? 1 : 0;
}

// ---- pack W0 into B-fragment order [nt][kt][lane][8], fp16; nt=7 zero-pad ----
__global__ void pack_w0(const float* __restrict__ W0, f16* __restrict__ ph) {
    int idx = blockIdx.x * 256 + threadIdx.x;
    if (idx >= NT0P * KT0 * 64) return;
    int lane = idx & 63;
    int ktn  = idx >> 6;
    int nt = ktn / KT0, kt = ktn % KT0;
    int col = nt * 16 + (lane & 15);
    #pragma unroll
    for (int e = 0; e < 8; ++e) {
        int k = kt * 32 + (lane >> 4) * 8 + e;
        int kr = -1;
        if (kt < 3) { if (k < NAF) kr = k; }
        else {
            int kk = k - kt * 32;
            if (kk < NGF) kr = NAF + (kt - 3) * NGF + kk;
        }
        float wv = (kr >= 0 && col < H) ? W0[(size_t)kr * H + col] : 0.f;
        ph[(size_t)idx * 8 + e] = (f16)wv;
    }
}

// ---- pack W1 [nt][kt][lane][8], hi + scaled lo ----
__global__ void pack_w1(const float* __restrict__ W1, f16* __restrict__ ph, f16* __restrict__ pl) {
    int idx = blockIdx.x * 256 + threadIdx.x;
    if (idx >= NT1 * KT1 * 64) return;
    int lane = idx & 63;
    int ktn  = idx >> 6;
    int nt = ktn / KT1, kt = ktn % KT1;
    int col = nt * 16 + (lane & 15);
    #pragma unroll
    for (int e = 0; e < 8; ++e) {
        int k = kt * 32 + (lane >> 4) * 8 + e;
        float wv = (k < H && col < NGF) ? W1[(size_t)k * NGF + col] : 0.f;
        f16 hi = (f16)wv;
        ph[(size_t)idx * 8 + e] = hi;
        pl[(size_t)idx * 8 + e] = (f16)((wv - (float)hi) * 1024.f);
    }
}

__global__ __launch_bounds__(NTHR, 2) void dag_mfma(
    const float* __restrict__ af,      // (NA, NAF) f32
    const int*   __restrict__ parents, // (NA, MA, MA)
    const int*   __restrict__ orders,  // (NA, MA)
    const void*  __restrict__ cmask,   // (NA, MA)
    const float* __restrict__ b0,
    const float* __restrict__ b1,
    const f16*   __restrict__ w0h,
    const f16*   __restrict__ w1h, const f16* __restrict__ w1l,
    const int*   __restrict__ flagp,
    float*       __restrict__ dout)    // (NA, NGF)
{
    // gf state: slot-major [51][32 rows][32 f16], full-address element-XOR
    // swizzle  addr = (slot*1024 + r*32 + c) ^ ((r&7)<<3).
    // Write and read use IDENTICAL XOR semantics (round-7 bug: read used
    // add-scoped XOR, scrambling rows where r&4 and r&1 differ).
    __shared__ f16     gfh[51 * 1024];     // 104,448 B
    __shared__ f16     afh[RPB][AFW];      //   6,656 B
    __shared__ f16     hh[RPB][HHW];       //   8,704 B
    __shared__ f32x4   part[4][2][2][64];  //  16,384 B  K-half partials
    __shared__ float   outl[RPB][33];      //   4,224 B
    __shared__ uint8_t slots[RPB][52];     //   1,664 B
    __shared__ int     colc[RPB];          //     128 B
    __shared__ int     maskc[RPB];         //     128 B
    __shared__ int     ordl[2][RPB];       //     256 B
    // total 142,592 B -> 1 block/CU, 8 waves

    const int tid   = threadIdx.x;
    const int w     = tid >> 6;
    const int lane  = tid & 63;
    const int mrow  = lane & 15;   // row within M-tile / output col
    const int kg    = lane >> 4;   // k-octet group
    const int npair = w & 3;       // N-tile pair index (nt = 2*npair, 2*npair+1)
    const int half  = w >> 2;      // K-half (0: kt 0..25, 1: kt 26..51)
    const int row0  = blockIdx.x * RPB;
    const int flag  = *flagp;

    // swizzled per-lane gfh bases (FULL-address XOR, matching the write path)
    const int base0 = (mrow * 32 + kg * 8)        ^ ((mrow & 7) << 3);
    const int base1 = ((16 + mrow) * 32 + kg * 8) ^ ((mrow & 7) << 3);

    // per-lane bias constants
    const int hc0 = npair * 32 + mrow;        // waves 0-3: h cols
    const int hc1 = npair * 32 + 16 + mrow;
    const float b0v0 = (w < 4 && hc0 < H) ? b0[hc0] : 0.f;
    const float b0v1 = (w < 4 && hc1 < H) ? b0[hc1] : 0.f;
    const int oc = (w - 4) * 16 + mrow;       // waves 4,5: out col
    const float b1v = (w >= 4 && w < 6 && oc < NGF) ? b1[oc] : 0.f;

    // ---- zero LDS state (pads stay zero forever) ----
    {
        f16x8 z = 0;
        for (int e = tid; e < 51 * 128; e += NTHR) ((f16x8*)gfh)[e] = z;
        for (int e = tid; e < RPB * AFW / 8; e += NTHR) ((f16x8*)&afh[0][0])[e] = z;
        for (int e = tid; e < RPB * HHW / 8; e += NTHR) ((f16x8*)&hh[0][0])[e]  = z;
    }
    if (tid >= 384 && tid < 416) {
        int r = tid - 384;
        ordl[0][r] = orders[(size_t)(row0 + r) * MA];
    }
    __syncthreads();

    float afr0 = 0.f, afr1 = 0.f, afr2 = 0.f, afr3 = 0.f, afr4 = 0.f;
    int   slr0 = 0, slr1 = 0, slr2 = 0, slr3 = 0;
    int   colr = 0, mskr = 0, oreg = 0;

    // issue gather loads for step T into regs (af rows via ordl[T&1])
    auto LOADS = [&](int T) {
        const int* ordb = ordl[T & 1];
        {
            int idx, r, k;
            idx = tid;        r = idx / NAF; k = idx - r * NAF; afr0 = af[(size_t)ordb[r] * NAF + k];
            idx = tid + 512;  r = idx / NAF; k = idx - r * NAF; afr1 = af[(size_t)ordb[r] * NAF + k];
            idx = tid + 1024; r = idx / NAF; k = idx - r * NAF; afr2 = af[(size_t)ordb[r] * NAF + k];
            idx = tid + 1536; r = idx / NAF; k = idx - r * NAF; afr3 = af[(size_t)ordb[r] * NAF + k];
            if (tid < 352) {
                idx = tid + 2048; r = idx / NAF; k = idx - r * NAF;
                afr4 = af[(size_t)ordb[r] * NAF + k];
            }
        }
        {
            int idx, r, p;
            idx = tid;        r = idx / 49; p = idx - r * 49;
            slr0 = __builtin_nontemporal_load(&parents[((size_t)(row0 + r) * MA + T) * MA + 1 + p]);
            idx = tid + 512;  r = idx / 49; p = idx - r * 49;
            slr1 = __builtin_nontemporal_load(&parents[((size_t)(row0 + r) * MA + T) * MA + 1 + p]);
            idx = tid + 1024; r = idx / 49; p = idx - r * 49;
            slr2 = __builtin_nontemporal_load(&parents[((size_t)(row0 + r) * MA + T) * MA + 1 + p]);
            if (tid < 32) {
                idx = tid + 1536; r = idx / 49; p = idx - r * 49;
                slr3 = __builtin_nontemporal_load(&parents[((size_t)(row0 + r) * MA + T) * MA + 1 + p]);
            }
        }
        if (tid >= 416 && tid < 448) {
            int r = tid - 416;
            colr = __builtin_nontemporal_load(&parents[((size_t)(row0 + r) * MA + T) * MA]);
        }
        if (tid >= 448 && tid < 480) {
            int r = tid - 448;
            if (flag) mskr = (int)__builtin_nontemporal_load(&((const uint8_t*)cmask)[(size_t)(row0 + r) * MA + T]);
            else      mskr = __builtin_nontemporal_load(&((const int*)cmask)[(size_t)(row0 + r) * MA + T]);
        }
        if (T + 1 < MA && tid >= 384 && tid < 416) {
            int r = tid - 384;
            oreg = __builtin_nontemporal_load(&orders[(size_t)(row0 + r) * MA + T + 1]);
        }
    };

    LOADS(0);

    for (int t = 0; t < MA; ++t) {
        // ---- phase A: commit staged gather(t) to LDS ----
        {
            int idx, r, k;
            idx = tid;        r = idx / NAF; k = idx - r * NAF; afh[r][k] = (f16)afr0;
            idx = tid + 512;  r = idx / NAF; k = idx - r * NAF; afh[r][k] = (f16)afr1;
            idx = tid + 1024; r = idx / NAF; k = idx - r * NAF; afh[r][k] = (f16)afr2;
            idx = tid + 1536; r = idx / NAF; k = idx - r * NAF; afh[r][k] = (f16)afr3;
            if (tid < 352) { idx = tid + 2048; r = idx / NAF; k = idx - r * NAF; afh[r][k] = (f16)afr4; }
        }
        {
            int idx, r, p;
            idx = tid;        r = idx / 49; p = idx - r * 49; slots[r][p] = (uint8_t)slr0;
            idx = tid + 512;  r = idx / 49; p = idx - r * 49; slots[r][p] = (uint8_t)slr1;
            idx = tid + 1024; r = idx / 49; p = idx - r * 49; slots[r][p] = (uint8_t)slr2;
            if (tid < 32) { idx = tid + 1536; r = idx / 49; p = idx - r * 49; slots[r][p] = (uint8_t)slr3; }
        }
        if (tid >= 416 && tid < 448) colc[tid - 416]  = colr;
        if (tid >= 448 && tid < 480) maskc[tid - 448] = mskr;
        if (t + 1 < MA && tid >= 384 && tid < 416) ordl[(t + 1) & 1][tid - 384] = oreg;
        __syncthreads();

        // ---- phase B: issue gather loads for t+1 (hidden under MFMA) ----
        if (t + 1 < MA) LOADS(t + 1);

        // ---- phase C: all 8 waves, K-split J=2 GEMM; B streamed from L2 ----
        f32x4 acc00 = {0.f,0.f,0.f,0.f}, acc01 = {0.f,0.f,0.f,0.f};
        f32x4 acc10 = {0.f,0.f,0.f,0.f}, acc11 = {0.f,0.f,0.f,0.f};
        {
            const f16x8* B0 = (const f16x8*)w0h + ((size_t)(2 * npair) * KT0 + half * 26) * 64 + lane;
            const f16x8* B1 = B0 + (size_t)KT0 * 64;
            if (half == 0) {
                #pragma unroll
                for (int kt = 0; kt < 3; ++kt) {     // atom-feature k-tiles
                    f16x8 a0 = *(const f16x8*)&afh[mrow][kt * 32 + kg * 8];
                    f16x8 a1 = *(const f16x8*)&afh[16 + mrow][kt * 32 + kg * 8];
                    f16x8 bb0 = B0[(size_t)kt * 64];
                    f16x8 bb1 = B1[(size_t)kt * 64];
                    acc00 = MFMA16(a0, bb0, acc00); acc10 = MFMA16(a1, bb0, acc10);
                    acc01 = MFMA16(a0, bb1, acc01); acc11 = MFMA16(a1, bb1, acc11);
                }
                #pragma unroll
                for (int g = 0; g < 23; ++g) {       // slots p = 0..22 (kt 3..25)
                    int s0 = slots[mrow][g];
                    int s1 = slots[16 + mrow][g];
                    f16x8 a0 = *(const f16x8*)&gfh[s0 * 1024 + base0];
                    f16x8 a1 = *(const f16x8*)&gfh[s1 * 1024 + base1];
                    f16x8 bb0 = B0[(size_t)(3 + g) * 64];
                    f16x8 bb1 = B1[(size_t)(3 + g) * 64];
                    acc00 = MFMA16(a0, bb0, acc00); acc10 = MFMA16(a1, bb0, acc10);
                    acc01 = MFMA16(a0, bb1, acc01); acc11 = MFMA16(a1, bb1, acc11);
                }
            } else {
                #pragma unroll
                for (int g = 0; g < 26; ++g) {       // slots p = 23..48 (kt 26..51)
                    int s0 = slots[mrow][23 + g];
                    int s1 = slots[16 + mrow][23 + g];
                    f16x8 a0 = *(const f16x8*)&gfh[s0 * 1024 + base0];
                    f16x8 a1 = *(const f16x8*)&gfh[s1 * 1024 + base1];
                    f16x8 bb0 = B0[(size_t)g * 64];
                    f16x8 bb1 = B1[(size_t)g * 64];
                    acc00 = MFMA16(a0, bb0, acc00); acc10 = MFMA16(a1, bb0, acc10);
                    acc01 = MFMA16(a0, bb1, acc01); acc11 = MFMA16(a1, bb1, acc11);
                }
            }
        }
        if (half) {
            part[npair][0][0][lane] = acc00;
            part[npair][0][1][lane] = acc01;
            part[npair][1][0][lane] = acc10;
            part[npair][1][1][lane] = acc11;
        }
        __syncthreads();

        // ---- phase R: waves 0-3 reduce K-halves, bias+relu, write hh ----
        if (!half) {
            acc00 += part[npair][0][0][lane];
            acc01 += part[npair][0][1][lane];
            acc10 += part[npair][1][0][lane];
            acc11 += part[npair][1][1][lane];
            #pragma unroll
            for (int i = 0; i < 4; ++i) {
                hh[kg * 4 + i][hc0]      = (f16)fmaxf(acc00[i] + b0v0, 0.f);
                hh[kg * 4 + i][hc1]      = (f16)fmaxf(acc01[i] + b0v1, 0.f);
                hh[16 + kg * 4 + i][hc0] = (f16)fmaxf(acc10[i] + b0v0, 0.f);
                hh[16 + kg * 4 + i][hc1] = (f16)fmaxf(acc11[i] + b0v1, 0.f);
            }
        }
        __syncthreads();

        // ---- phase D: waves 4,5: out = relu(h @ W1 + b1) (hi/lo) ----
        if (w == 4 || w == 5) {
            const int nt2 = w - 4;
            f32x4 h00 = {0.f,0.f,0.f,0.f}, l00 = {0.f,0.f,0.f,0.f};
            f32x4 h10 = {0.f,0.f,0.f,0.f}, l10 = {0.f,0.f,0.f,0.f};
            const f16x8* Bh = (const f16x8*)w1h + (size_t)nt2 * KT1 * 64 + lane;
            const f16x8* Bl = (const f16x8*)w1l + (size_t)nt2 * KT1 * 64 + lane;
            #pragma unroll
            for (int kt = 0; kt < KT1; ++kt) {
                f16x8 a0 = *(const f16x8*)&hh[mrow][kt * 32 + kg * 8];
                f16x8 a1 = *(const f16x8*)&hh[16 + mrow][kt * 32 + kg * 8];
                f16x8 bh = Bh[(size_t)kt * 64];
                f16x8 bl = Bl[(size_t)kt * 64];
                h00 = MFMA16(a0, bh, h00); l00 = MFMA16(a0, bl, l00);
                h10 = MFMA16(a1, bh, h10); l10 = MFMA16(a1, bl, l10);
            }
            if (oc < NGF) {
                #pragma unroll
                for (int i = 0; i < 4; ++i) {
                    outl[kg * 4 + i][oc]      = fmaxf(h00[i] + l00[i] * (1.f/1024.f) + b1v, 0.f);
                    outl[16 + kg * 4 + i][oc] = fmaxf(h10[i] + l10[i] * (1.f/1024.f) + b1v, 0.f);
                }
            }
        }
        __syncthreads();

        // ---- phase E: masked scatter into swizzled gfh; final dout at t=49 ----
        {
            int e = tid;
            #pragma unroll
            for (int q = 0; q < 2; ++q, e += NTHR) {
                if (e < RPB * NGF) {
                    int r = e / NGF, c = e - r * NGF;
                    float v = outl[r][c];
                    if (maskc[r])
                        gfh[(colc[r] * 1024 + r * 32 + c) ^ ((r & 7) << 3)] = (f16)v;
                    if (t == MA - 1)
                        dout[(size_t)(row0 + r) * NGF + c] = maskc[r] ? v : 0.f;
                }
            }
        }
        __syncthreads();
    }
}

extern "C" void kernel_launch(void* const* d_in, const int* in_sizes, int n_in,
                              void* d_out, int out_size, void* d_ws, size_t ws_size,
                              hipStream_t stream) {
    const float* af      = (const float*)d_in[0];
    const int*   parents = (const int*)  d_in[1];
    const int*   orders  = (const int*)  d_in[2];
    const void*  cmask   =               d_in[3];
    // d_in[4] = n_atoms scalar, unused
    const float* W0      = (const float*)d_in[5];
    const float* b0      = (const float*)d_in[6];
    const float* W1      = (const float*)d_in[7];
    const float* b1      = (const float*)d_in[8];

    char* ws = (char*)d_ws;
    f16* w0h = (f16*)(ws);               // 8*52*64*8*2 = 425,984 B
    f16* w1h = (f16*)(ws + 425984);      //   8,192 B
    f16* w1l = (f16*)(ws + 434176);      //   8,192 B
    int* flagp = (int*)(ws + 442368);
    float* dout = (float*)d_out;

    detect_mask<<<1, 64, 0, stream>>>((const uint8_t*)cmask, flagp);
    pack_w0<<<(NT0P * KT0 * 64 + 255) / 256, 256, 0, stream>>>(W0, w0h);
    pack_w1<<<(NT1 * KT1 * 64 + 255) / 256, 256, 0, stream>>>(W1, w1h, w1l);

    dag_mfma<<<NA / RPB, NTHR, 0, stream>>>(
        af, parents, orders, cmask, b0, b1, w0h, w1h, w1l, flagp, dout);
}